// Round 4
// baseline (93.111 us; speedup 1.0000x reference)
//
#include <hip/hip_runtime.h>
#include <math.h>

// Problem constants (fixed by setup_inputs)
constexpr int kB = 16, kN = 900, kC = 92, kT = 960;
constexpr int kBN = kB * kN;          // 14400 rows
constexpr int ROWS = 4;               // rows per block (one wave each for softmax)
constexpr int THREADS = 256;

typedef float nt_float4 __attribute__((ext_vector_type(4)));  // native vec for nontemporal store

__global__ __launch_bounds__(THREADS) void matcher_kernel(
    const float* __restrict__ out_labels,   // [BN, C]
    const float* __restrict__ out_bboxes,   // [BN, 4] cxcywh
    const int*   __restrict__ tgt_labels,   // [T]
    const float* __restrict__ tgt_bboxes,   // [T, 4] used as-is (xyxy per reference NOTE)
    float*       __restrict__ cost)         // [BN, T]
{
    __shared__ float4 s_tb[kT];             // 15360 B
    __shared__ int    s_lab[kT];            // 3840 B
    // Class-cost table TRANSPOSED: s_cl4[c] = {5-prob_r0(c), .., 5-prob_r3(c)}
    // -> one ds_read_b128 gather per (thread,target) serves all 4 rows.
    __shared__ float4 s_cl4[kC];            // 1472 B
    __shared__ float4 s_rowA[ROWS];         // cx,cy,w,h
    __shared__ float4 s_rowB[ROWS];         // bx0,by0,bx1,by1
    __shared__ float  s_rowC[ROWS];         // area1

    const int tid  = threadIdx.x;
    const int row0 = blockIdx.x * ROWS;

    // Stage target data into LDS (coalesced float4 / int loads)
    const float4* tb4 = (const float4*)tgt_bboxes;
    for (int i = tid; i < kT; i += THREADS) {
        s_tb[i]  = tb4[i];
        s_lab[i] = tgt_labels[i];
    }

    // Per-row softmax: wave r handles row r (C=92 -> lanes cover [0,64) and [64,92))
    {
        const int r = tid >> 6;
        const int lane = tid & 63;
        const int p = row0 + r;
        const float* lrow = out_labels + (size_t)p * kC;
        float x0 = (lane < kC)      ? lrow[lane]      : -INFINITY;
        float x1 = (lane + 64 < kC) ? lrow[lane + 64] : -INFINITY;
        float m = fmaxf(x0, x1);
        #pragma unroll
        for (int off = 32; off > 0; off >>= 1)
            m = fmaxf(m, __shfl_down(m, off, 64));
        m = __shfl(m, 0, 64);
        float e0 = (lane < kC)      ? expf(x0 - m) : 0.0f;
        float e1 = (lane + 64 < kC) ? expf(x1 - m) : 0.0f;
        float s = e0 + e1;
        #pragma unroll
        for (int off = 32; off > 0; off >>= 1)
            s += __shfl_down(s, off, 64);
        s = __shfl(s, 0, 64);
        float inv = 1.0f / s;
        // transposed write: class c, row r -> flat [c*4 + r]
        float* clf = (float*)s_cl4;
        if (lane < kC)      clf[lane * 4 + r]        = 5.0f - e0 * inv;
        if (lane + 64 < kC) clf[(lane + 64) * 4 + r] = 5.0f - e1 * inv;
        if (lane == 0) {
            float4 bb = ((const float4*)out_bboxes)[p];
            float hw = 0.5f * bb.z, hh = 0.5f * bb.w;
            float bx0 = bb.x - hw, by0 = bb.y - hh;
            float bx1 = bb.x + hw, by1 = bb.y + hh;
            s_rowA[r] = bb;
            s_rowB[r] = make_float4(bx0, by0, bx1, by1);
            s_rowC[r] = (bx1 - bx0) * (by1 - by0);   // area1, same order as ref
        }
    }
    __syncthreads();

    // Pair phase: each thread owns 4 consecutive targets (t0..t0+3), loops rows.
    const int t0 = tid * 4;
    if (t0 < kT) {
        // Hoist per-target data into registers (reused across all 4 rows)
        float4 tb[4]; float a2[4]; float4 cls[4];
        #pragma unroll
        for (int i = 0; i < 4; ++i) {
            tb[i]  = s_tb[t0 + i];
            a2[i]  = (tb[i].z - tb[i].x) * (tb[i].w - tb[i].y);
            cls[i] = s_cl4[s_lab[t0 + i]];   // 1 b128 gather -> 4 rows' class costs
        }
        #pragma unroll
        for (int r = 0; r < ROWS; ++r) {
            const int p = row0 + r;
            float4 ra = s_rowA[r];          // cx,cy,w,h   (LDS broadcast)
            float4 rb = s_rowB[r];          // bx0,by0,bx1,by1
            float area1 = s_rowC[r];
            nt_float4 res;
            #pragma unroll
            for (int i = 0; i < 4; ++i) {
                float4 t = tb[i];
                // L1 on raw cxcywh vs target (torch.cdist p=1 semantics)
                float l1 = fabsf(ra.x - t.x) + fabsf(ra.y - t.y)
                         + fabsf(ra.z - t.z) + fabsf(ra.w - t.w);
                // intersection (clamp needed)
                float ltx = fmaxf(rb.x, t.x), lty = fmaxf(rb.y, t.y);
                float rbx = fminf(rb.z, t.z), rby = fminf(rb.w, t.w);
                float iw = fmaxf(rbx - ltx, 0.0f), ih = fmaxf(rby - lty, 0.0f);
                float inter = iw * ih;
                float uni = area1 + a2[i] - inter;
                // enclosing box (clamp is a no-op: pred w,h >= 0 ⇒ ex1>=ex0, ey1>=ey0)
                float ex0 = fminf(rb.x, t.x), ey0 = fminf(rb.y, t.y);
                float ex1 = fmaxf(rb.z, t.z), ey1 = fmaxf(rb.w, t.w);
                float area_e = (ex1 - ex0) * (ey1 - ey0);
                // cost = (5 - prob) + 5*L1 - 2*inter/uni - 2*uni/area_e
                float rcpu = __builtin_amdgcn_rcpf(uni);
                float rcpe = __builtin_amdgcn_rcpf(area_e);
                float v = (r == 0) ? cls[i].x : (r == 1) ? cls[i].y
                        : (r == 2) ? cls[i].z : cls[i].w;
                v = fmaf(5.0f, l1, v);
                v = fmaf(-2.0f * inter, rcpu, v);
                v = fmaf(-2.0f * uni, rcpe, v);
                res[i] = v;
            }
            __builtin_nontemporal_store(res, (nt_float4*)(cost + (size_t)p * kT) + tid);
        }
    }
}

extern "C" void kernel_launch(void* const* d_in, const int* in_sizes, int n_in,
                              void* d_out, int out_size, void* d_ws, size_t ws_size,
                              hipStream_t stream) {
    const float* out_labels = (const float*)d_in[0];
    const float* out_bboxes = (const float*)d_in[1];
    const int*   tgt_labels = (const int*)d_in[2];
    const float* tgt_bboxes = (const float*)d_in[3];
    float* cost = (float*)d_out;
    dim3 grid(kBN / ROWS);   // 14400/4 = 3600 blocks
    matcher_kernel<<<grid, THREADS, 0, stream>>>(out_labels, out_bboxes,
                                                 tgt_labels, tgt_bboxes, cost);
}

// Round 5
// 90.556 us; speedup vs baseline: 1.0282x; 1.0282x over previous
//
#include <hip/hip_runtime.h>
#include <math.h>

// Problem constants (fixed by setup_inputs)
constexpr int kB = 16, kN = 900, kC = 92, kT = 960;
constexpr int kBN = kB * kN;          // 14400 rows
constexpr int ROWS = 4;               // rows per block (one wave each for softmax)
constexpr int THREADS = 256;

typedef float nt_float4 __attribute__((ext_vector_type(4)));  // native vec for nontemporal store

__global__ __launch_bounds__(THREADS) void matcher_kernel(
    const float* __restrict__ out_labels,   // [BN, C]
    const float* __restrict__ out_bboxes,   // [BN, 4] cxcywh
    const int*   __restrict__ tgt_labels,   // [T]
    const float* __restrict__ tgt_bboxes,   // [T, 4] used as-is (xyxy per reference NOTE)
    float*       __restrict__ cost)         // [BN, T]
{
    // Class-cost table TRANSPOSED: s_cl4[c] = {5-prob_r0(c), .., 5-prob_r3(c)}
    // -> one ds_read_b128 gather per (thread,target) serves all 4 rows.
    __shared__ float4 s_cl4[kC];            // 1472 B
    __shared__ float4 s_rowA[ROWS];         // cx,cy,w,h
    __shared__ float4 s_rowB[ROWS];         // bx0,by0,bx1,by1
    __shared__ float  s_rowC[ROWS];         // area1

    const int tid  = threadIdx.x;
    const int row0 = blockIdx.x * ROWS;

    // NOTE: no LDS staging of targets — each target is consumed by exactly one
    // thread (tid = t/4) and held in registers across all 4 rows, so
    // global->LDS->reg would be strictly more work than global->reg.
    // Targets (19 KB) are L1-resident per CU after the first block.
    const int t0 = tid * 4;
    float4 tb[4]; float a2[4]; int4 lab;
    if (t0 < kT) {
        const float4* tb4 = (const float4*)tgt_bboxes;
        #pragma unroll
        for (int i = 0; i < 4; ++i) tb[i] = tb4[t0 + i];
        lab = ((const int4*)tgt_labels)[tid];
        #pragma unroll
        for (int i = 0; i < 4; ++i)
            a2[i] = (tb[i].z - tb[i].x) * (tb[i].w - tb[i].y);
    }

    // Per-row softmax: wave r handles row r (C=92 -> lanes cover [0,64) and [64,92))
    {
        const int r = tid >> 6;
        const int lane = tid & 63;
        const int p = row0 + r;
        const float* lrow = out_labels + (size_t)p * kC;
        float x0 = (lane < kC)      ? lrow[lane]      : -INFINITY;
        float x1 = (lane + 64 < kC) ? lrow[lane + 64] : -INFINITY;
        float m = fmaxf(x0, x1);
        #pragma unroll
        for (int off = 32; off > 0; off >>= 1)
            m = fmaxf(m, __shfl_down(m, off, 64));
        m = __shfl(m, 0, 64);
        float e0 = (lane < kC)      ? expf(x0 - m) : 0.0f;
        float e1 = (lane + 64 < kC) ? expf(x1 - m) : 0.0f;
        float s = e0 + e1;
        #pragma unroll
        for (int off = 32; off > 0; off >>= 1)
            s += __shfl_down(s, off, 64);
        s = __shfl(s, 0, 64);
        float inv = 1.0f / s;
        // transposed write: class c, row r -> flat [c*4 + r]
        float* clf = (float*)s_cl4;
        if (lane < kC)      clf[lane * 4 + r]        = 5.0f - e0 * inv;
        if (lane + 64 < kC) clf[(lane + 64) * 4 + r] = 5.0f - e1 * inv;
        if (lane == 0) {
            float4 bb = ((const float4*)out_bboxes)[p];
            float hw = 0.5f * bb.z, hh = 0.5f * bb.w;
            float bx0 = bb.x - hw, by0 = bb.y - hh;
            float bx1 = bb.x + hw, by1 = bb.y + hh;
            s_rowA[r] = bb;
            s_rowB[r] = make_float4(bx0, by0, bx1, by1);
            s_rowC[r] = (bx1 - bx0) * (by1 - by0);   // area1, same order as ref
        }
    }
    __syncthreads();

    // Pair phase: each thread owns 4 consecutive targets (t0..t0+3), loops rows.
    if (t0 < kT) {
        float4 cls[4];
        cls[0] = s_cl4[lab.x];   // 1 b128 gather -> 4 rows' class costs
        cls[1] = s_cl4[lab.y];
        cls[2] = s_cl4[lab.z];
        cls[3] = s_cl4[lab.w];
        #pragma unroll
        for (int r = 0; r < ROWS; ++r) {
            const int p = row0 + r;
            float4 ra = s_rowA[r];          // cx,cy,w,h   (LDS broadcast)
            float4 rb = s_rowB[r];          // bx0,by0,bx1,by1
            float area1 = s_rowC[r];
            nt_float4 res;
            #pragma unroll
            for (int i = 0; i < 4; ++i) {
                float4 t = tb[i];
                // L1 on raw cxcywh vs target (torch.cdist p=1 semantics)
                float l1 = fabsf(ra.x - t.x) + fabsf(ra.y - t.y)
                         + fabsf(ra.z - t.z) + fabsf(ra.w - t.w);
                // intersection (clamp needed)
                float ltx = fmaxf(rb.x, t.x), lty = fmaxf(rb.y, t.y);
                float rbx = fminf(rb.z, t.z), rby = fminf(rb.w, t.w);
                float iw = fmaxf(rbx - ltx, 0.0f), ih = fmaxf(rby - lty, 0.0f);
                float inter = iw * ih;
                float uni = area1 + a2[i] - inter;
                // enclosing box (clamp is a no-op: pred w,h >= 0 ⇒ ex1>=ex0, ey1>=ey0)
                float ex0 = fminf(rb.x, t.x), ey0 = fminf(rb.y, t.y);
                float ex1 = fmaxf(rb.z, t.z), ey1 = fmaxf(rb.w, t.w);
                float area_e = (ex1 - ex0) * (ey1 - ey0);
                // cost = (5-prob) + 5*L1 - 2*(inter/uni + uni/area_e)
                //      = (5-prob) + 5*L1 - 2*(inter*area_e + uni^2)/(uni*area_e)
                float num = fmaf(uni, uni, inter * area_e);
                float rcp = __builtin_amdgcn_rcpf(uni * area_e);
                float v = (r == 0) ? cls[i].x : (r == 1) ? cls[i].y
                        : (r == 2) ? cls[i].z : cls[i].w;
                v = fmaf(5.0f, l1, v);
                v = fmaf(-2.0f * num, rcp, v);
                res[i] = v;
            }
            __builtin_nontemporal_store(res, (nt_float4*)(cost + (size_t)p * kT) + tid);
        }
    }
}

extern "C" void kernel_launch(void* const* d_in, const int* in_sizes, int n_in,
                              void* d_out, int out_size, void* d_ws, size_t ws_size,
                              hipStream_t stream) {
    const float* out_labels = (const float*)d_in[0];
    const float* out_bboxes = (const float*)d_in[1];
    const int*   tgt_labels = (const int*)d_in[2];
    const float* tgt_bboxes = (const float*)d_in[3];
    float* cost = (float*)d_out;
    dim3 grid(kBN / ROWS);   // 14400/4 = 3600 blocks
    matcher_kernel<<<grid, THREADS, 0, stream>>>(out_labels, out_bboxes,
                                                 tgt_labels, tgt_bboxes, cost);
}